// Round 1
// baseline (214.346 us; speedup 1.0000x reference)
//
#include <hip/hip_runtime.h>

#define NEMB 512
#define EMB 64
#define BSTR 262144          // 64*4096
#define DECAYF 0.99f
#define OMDF 0.01f
#define EPSF 1e-5f
#define GAP_T 0.012f
#define QCAP 32768           // flagged-token queue capacity (expect ~2-8K)

typedef __attribute__((ext_vector_type(8))) short bf16x8;
typedef __attribute__((ext_vector_type(4))) float f32x4;

__device__ __forceinline__ unsigned short f2bf(float f) {
    unsigned u = __float_as_uint(f);
    return (unsigned short)((u + 0x7FFFu + ((u >> 16) & 1u)) >> 16);   // RNE
}
__device__ __forceinline__ float bf2f(unsigned short h) {
    return __uint_as_float(((unsigned)h) << 16);
}

// 9 blocks x 512 threads.
// blocks 0-7: split w into bf16 hi/lo transposed [n][k].
// block 8: wsq + zero cnt_ws (512) + zero es region (32768) + zero flag queue count.
__global__ void prep_kernel(const float* __restrict__ w,
                            unsigned short* __restrict__ wh, unsigned short* __restrict__ wl,
                            float* __restrict__ wsq,
                            float* __restrict__ cnt_ws, float* __restrict__ es_region,
                            unsigned* __restrict__ gcnt) {
    int j = threadIdx.x;
    if (blockIdx.x < 8) {
        int d0 = blockIdx.x << 3;
        bf16x8 hb, lb;
#pragma unroll
        for (int i = 0; i < 8; ++i) {
            float v = w[(d0 + i) * NEMB + j];
            unsigned short h = f2bf(v);
            hb[i] = (short)h;
            lb[i] = (short)f2bf(v - bf2f(h));
        }
        *(bf16x8*)(wh + j * EMB + d0) = hb;
        *(bf16x8*)(wl + j * EMB + d0) = lb;
    } else {
        float s = 0.f;
#pragma unroll
        for (int d = 0; d < EMB; ++d) { float v = w[d * NEMB + j]; s = fmaf(v, v, s); }
        wsq[j] = s;
        cnt_ws[j] = 0.f;
        if (j == 0) *gcnt = 0u;
#pragma unroll
        for (int k = j; k < 32768; k += 512) es_region[k] = 0.f;
    }
}

#define UPD(S1, J1, S2, J2, s_, j_) do { \
    if (s_ < S1 || (s_ == S1 && j_ < J1)) { S2 = S1; J2 = J1; S1 = s_; J1 = j_; } \
    else if (s_ < S2 || (s_ == S2 && j_ < J2)) { S2 = s_; J2 = j_; } } while (0)

// 2048 blocks x 128 threads: one h-row (64 tokens) per block, 2 waves x 32 tokens.
// No xt LDS: A-fragments built directly from global x. Each 128B x line (32 floats
// = one wave's 32 columns) is consumed entirely by that wave's mt=0/mt=1 reads, so
// HBM traffic stays ~1x. This removes 32KB LDS + 3 barriers + the staged ds_read
// round-trip, and lets more blocks cover latency.
// Code fragments (wh/wl) are register-prefetched one iteration ahead to hide L2 latency.
// Near-tie tokens are pushed to a GLOBAL queue; a separate balanced refine kernel
// resolves them (the old inline wave-per-token refine was ~2/3 of this kernel's VALU
// time and created a per-block straggler tail with no spare blocks to fill it).
__global__ __launch_bounds__(128, 4) void vq_main(
    const float* __restrict__ x,
    const unsigned short* __restrict__ wh, const unsigned short* __restrict__ wl,
    const float* __restrict__ wsq,
    float* __restrict__ out_arg, unsigned* __restrict__ gcnt, int* __restrict__ queue)
{
    __shared__ float wsq_s[NEMB];

    const int tid = threadIdx.x;
    const int blk = blockIdx.x;          // 2048
    const int b   = blk >> 6;
    const int h   = blk & 63;
    const int t0  = b * 4096 + h * 64;   // global token base (64 tokens)
    const float* xrow = x + b * BSTR + h * 64;

    wsq_s[tid]       = wsq[tid];
    wsq_s[tid + 128] = wsq[tid + 128];
    wsq_s[tid + 256] = wsq[tid + 256];
    wsq_s[tid + 384] = wsq[tid + 384];

    const int lane = tid & 63;
    const int wave = tid >> 6;           // 0..1
    const int l15  = lane & 15;
    const int quad = lane >> 4;
    const int wbase = wave << 5;         // 32 tokens per wave

    // A fragments (hi/lo) straight from global; fold in per-column ||x||^2.
    bf16x8 ah[2][2], al[2][2];
    float  xq[2][4];
#pragma unroll
    for (int mt = 0; mt < 2; ++mt) {
        const float* xp = xrow + wbase + (mt << 4) + l15;   // column for this lane
        float s = 0.f;
#pragma unroll
        for (int ks = 0; ks < 2; ++ks) {
            const int d0 = (ks << 5) + (quad << 3);
            bf16x8 hh, ll;
#pragma unroll
            for (int i = 0; i < 8; ++i) {
                float v = xp[(d0 + i) * 4096];
                s = fmaf(v, v, s);
                unsigned short hb = f2bf(v);
                hh[i] = (short)hb;
                ll[i] = (short)f2bf(v - bf2f(hb));
            }
            ah[mt][ks] = hh; al[mt][ks] = ll;
        }
        // cross-quad reduce: every lane gets the full column sum for its l15
        s += __shfl_xor(s, 16, 64);
        s += __shfl_xor(s, 32, 64);
        // redistribute to accumulator-row layout: row r of quad q = token q*4+r
#pragma unroll
        for (int r = 0; r < 4; ++r)
            xq[mt][r] = __shfl(s, (quad << 2) + r, 64);
    }
    __syncthreads();     // wsq_s ready

    float v1[2][4], v2[2][4];
    int   j1[2][4];
#pragma unroll
    for (int mt = 0; mt < 2; ++mt)
#pragma unroll
        for (int r = 0; r < 4; ++r) { v1[mt][r] = 3.4e38f; v2[mt][r] = 3.4e38f; j1[mt][r] = 0; }

    // register prefetch of next iteration's code fragments (hides L2 latency)
    const unsigned short* ph = wh + l15 * EMB + (quad << 3);
    const unsigned short* pl = wl + l15 * EMB + (quad << 3);
    bf16x8 nb0 = *(const bf16x8*)(ph);
    bf16x8 nb1 = *(const bf16x8*)(ph + 32);
    bf16x8 nb2 = *(const bf16x8*)(pl);
    bf16x8 nb3 = *(const bf16x8*)(pl + 32);

#pragma unroll 2
    for (int it = 0; it < 32; ++it) {
        bf16x8 b0 = nb0, b1 = nb1, b2 = nb2, b3 = nb3;
        if (it != 31) {
            ph += 1024; pl += 1024;     // 16 codes * 64 shorts
            nb0 = *(const bf16x8*)(ph);
            nb1 = *(const bf16x8*)(ph + 32);
            nb2 = *(const bf16x8*)(pl);
            nb3 = *(const bf16x8*)(pl + 32);
        }
        const int n = (it << 4) + l15;
        float wq = wsq_s[n];

        f32x4 acc0 = (f32x4){0.f, 0.f, 0.f, 0.f};
        f32x4 acc1 = (f32x4){0.f, 0.f, 0.f, 0.f};
        acc0 = __builtin_amdgcn_mfma_f32_16x16x32_bf16(ah[0][0], b0, acc0, 0, 0, 0);
        acc1 = __builtin_amdgcn_mfma_f32_16x16x32_bf16(ah[1][0], b0, acc1, 0, 0, 0);
        acc0 = __builtin_amdgcn_mfma_f32_16x16x32_bf16(ah[0][1], b1, acc0, 0, 0, 0);
        acc1 = __builtin_amdgcn_mfma_f32_16x16x32_bf16(ah[1][1], b1, acc1, 0, 0, 0);
        acc0 = __builtin_amdgcn_mfma_f32_16x16x32_bf16(ah[0][0], b2, acc0, 0, 0, 0);
        acc1 = __builtin_amdgcn_mfma_f32_16x16x32_bf16(ah[1][0], b2, acc1, 0, 0, 0);
        acc0 = __builtin_amdgcn_mfma_f32_16x16x32_bf16(ah[0][1], b3, acc0, 0, 0, 0);
        acc1 = __builtin_amdgcn_mfma_f32_16x16x32_bf16(ah[1][1], b3, acc1, 0, 0, 0);
        acc0 = __builtin_amdgcn_mfma_f32_16x16x32_bf16(al[0][0], b0, acc0, 0, 0, 0);
        acc1 = __builtin_amdgcn_mfma_f32_16x16x32_bf16(al[1][0], b0, acc1, 0, 0, 0);
        acc0 = __builtin_amdgcn_mfma_f32_16x16x32_bf16(al[0][1], b1, acc0, 0, 0, 0);
        acc1 = __builtin_amdgcn_mfma_f32_16x16x32_bf16(al[1][1], b1, acc1, 0, 0, 0);

#pragma unroll
        for (int r = 0; r < 4; ++r) {
            float s0 = fmaf(-2.f, acc0[r], xq[0][r] + wq);
            bool p0 = s0 < v1[0][r];
            float mx0 = fmaxf(s0, v1[0][r]);
            v1[0][r] = fminf(s0, v1[0][r]);
            v2[0][r] = fminf(v2[0][r], mx0);
            j1[0][r] = p0 ? n : j1[0][r];

            float s1 = fmaf(-2.f, acc1[r], xq[1][r] + wq);
            bool p1 = s1 < v1[1][r];
            float mx1 = fmaxf(s1, v1[1][r]);
            v1[1][r] = fminf(s1, v1[1][r]);
            v2[1][r] = fminf(v2[1][r], mx1);
            j1[1][r] = p1 ? n : j1[1][r];
        }
    }

    // butterfly merge (v1,j1,v2) across the 16 lanes sharing each token
#pragma unroll
    for (int mt = 0; mt < 2; ++mt)
#pragma unroll
        for (int r = 0; r < 4; ++r) {
            float a1 = v1[mt][r], a2 = v2[mt][r];
            int   aj = j1[mt][r];
#pragma unroll
            for (int msk = 1; msk < 16; msk <<= 1) {
                float o1 = __shfl_xor(a1, msk, 64);
                int   oj = __shfl_xor(aj, msk, 64);
                float o2 = __shfl_xor(a2, msk, 64);
                bool take = (o1 < a1) || (o1 == a1 && oj < aj);
                float mx = fmaxf(a1, o1);
                a2 = fminf(fminf(a2, o2), mx);
                a1 = fminf(a1, o1);
                aj = take ? oj : aj;
            }
            v1[mt][r] = a1; v2[mt][r] = a2; j1[mt][r] = aj;
        }

    if (l15 == 0) {
#pragma unroll
        for (int mt = 0; mt < 2; ++mt)
#pragma unroll
            for (int r = 0; r < 4; ++r) {
                int gt = t0 + wbase + (mt << 4) + (quad << 2) + r;
                out_arg[gt] = (float)j1[mt][r];
                if (v2[mt][r] - v1[mt][r] < GAP_T) {
                    unsigned idx = atomicAdd(gcnt, 1u);     // global queue
                    if (idx < QCAP) queue[idx] = gt;
                }
            }
    }
}

// Globally balanced exact refine: 256 blocks x 256 threads = 1024 waves, each wave
// grabs flagged tokens with stride 1024 (no per-block tail). Exact fp32 scan over
// all 512 codes + f64 tie-break — identical math to the old inline refine.
__global__ __launch_bounds__(256) void refine_kernel(
    const float* __restrict__ x, const float* __restrict__ w,
    const float* __restrict__ wsq, const unsigned* __restrict__ gcnt,
    const int* __restrict__ queue, float* __restrict__ out_arg)
{
    __shared__ float wsq_s[NEMB];
    const int tid = threadIdx.x;
    wsq_s[tid] = wsq[tid];
    wsq_s[tid + 256] = wsq[tid + 256];
    __syncthreads();

    unsigned nfu = *gcnt;
    const int nf = (int)(nfu < (unsigned)QCAP ? nfu : (unsigned)QCAP);
    const int lane = tid & 63;
    const int gw = (blockIdx.x << 2) + (tid >> 6);

    for (int i = gw; i < nf; i += 1024) {
        const int t = queue[i];
        const int b = t >> 12, pos = t & 4095;
        float xd = x[b * BSTR + lane * 4096 + pos];   // x column, d = lane (L3-resident)
        float xqv = xd * xd;
#pragma unroll
        for (int mk = 1; mk < 64; mk <<= 1) xqv += __shfl_xor(xqv, mk, 64);

        float accv[8];
#pragma unroll
        for (int k = 0; k < 8; ++k) accv[k] = 0.f;
#pragma unroll 4
        for (int d = 0; d < EMB; ++d) {
            float4 wa = *(const float4*)(w + d * NEMB + (lane << 2));
            float4 wb = *(const float4*)(w + d * NEMB + 256 + (lane << 2));
            float xv = __shfl(xd, d, 64);
            accv[0] = fmaf(xv, wa.x, accv[0]);
            accv[1] = fmaf(xv, wa.y, accv[1]);
            accv[2] = fmaf(xv, wa.z, accv[2]);
            accv[3] = fmaf(xv, wa.w, accv[3]);
            accv[4] = fmaf(xv, wb.x, accv[4]);
            accv[5] = fmaf(xv, wb.y, accv[5]);
            accv[6] = fmaf(xv, wb.z, accv[6]);
            accv[7] = fmaf(xv, wb.w, accv[7]);
        }

        float S1 = 3.4e38f, S2 = 3.4e38f; int J1 = 0, J2 = 0;
#pragma unroll
        for (int k = 0; k < 8; ++k) {
            int j = (k < 4) ? ((lane << 2) + k) : (256 + (lane << 2) + k - 4);
            float s = (xqv - 2.f * accv[k]) + wsq_s[j];
            UPD(S1, J1, S2, J2, s, j);
        }
#pragma unroll
        for (int mk = 1; mk < 64; mk <<= 1) {
            float os1 = __shfl_xor(S1, mk, 64); int oj1 = __shfl_xor(J1, mk, 64);
            float os2 = __shfl_xor(S2, mk, 64); int oj2 = __shfl_xor(J2, mk, 64);
            UPD(S1, J1, S2, J2, os1, oj1);
            UPD(S1, J1, S2, J2, os2, oj2);
        }

        int jm = J1;
        if (S2 - S1 < 1e-3f) {
            float w1 = w[lane * NEMB + J1];
            float w2 = w[lane * NEMB + J2];
            double e1 = (double)w1 * (double)w1 - 2.0 * (double)xd * (double)w1;
            double e2 = (double)w2 * (double)w2 - 2.0 * (double)xd * (double)w2;
#pragma unroll
            for (int mk = 1; mk < 64; mk <<= 1) {
                e1 += __shfl_xor(e1, mk, 64);
                e2 += __shfl_xor(e2, mk, 64);
            }
            if (e2 < e1 || (e2 == e1 && J2 < J1)) jm = J2;
        }
        if (lane == 0) out_arg[t] = (float)jm;
    }
}

// fused: result write + es/cnt accumulation. grid = 65 grp x 32 chunks (2080 blocks).
// 8-way replicated, bank-staggered LDS accumulators (stride 513 -> copy c of slot j
// lands in bank (j+c)%32): lanes with the same hot codeword split across 8 copies /
// 8 distinct banks, cutting the same-address atomic serialization up to 8x.
__global__ __launch_bounds__(256) void finish_kernel(
    const float* __restrict__ x, const float* __restrict__ w, const float* __restrict__ arg,
    float* __restrict__ out_result,
    float* __restrict__ es, float* __restrict__ cnt)
{
    __shared__ float wrow[NEMB];
    __shared__ float acc[8][513];
    const int tid = threadIdx.x;
    const int grp = blockIdx.x >> 5;     // 0..64
    const int chunk = blockIdx.x & 31;

    float* af = &acc[0][0];
#pragma unroll
    for (int k = tid; k < 8 * 513; k += 256) af[k] = 0.f;
    if (grp < 64) {
        wrow[tid] = w[grp * NEMB + tid];
        wrow[tid + 256] = w[grp * NEMB + tid + 256];
    }
    __syncthreads();

    const int c = tid & 7;               // this thread's accumulator copy
    const int tbase = chunk << 12;       // 4096 tokens per chunk
    if (grp < 64) {
        const int d = grp;
#pragma unroll 2
        for (int it = 0; it < 4; ++it) {
            int t = tbase + (it << 10) + (tid << 2);      // 4 consecutive tokens, same b
            int o = (t >> 12) * BSTR + d * 4096 + (t & 4095);
            float4 a4 = *(const float4*)(arg + t);
            float4 x4 = *(const float4*)(x + o);
            int j0 = (int)a4.x, j1 = (int)a4.y, j2 = (int)a4.z, j3 = (int)a4.w;
            atomicAdd(&acc[c][j0], x4.x);
            atomicAdd(&acc[c][j1], x4.y);
            atomicAdd(&acc[c][j2], x4.z);
            atomicAdd(&acc[c][j3], x4.w);
            float4 r4 = {wrow[j0], wrow[j1], wrow[j2], wrow[j3]};
            *(float4*)(out_result + o) = r4;
        }
    } else {
#pragma unroll 2
        for (int it = 0; it < 4; ++it) {
            int t = tbase + (it << 10) + (tid << 2);
            float4 a4 = *(const float4*)(arg + t);
            atomicAdd(&acc[c][(int)a4.x], 1.0f);
            atomicAdd(&acc[c][(int)a4.y], 1.0f);
            atomicAdd(&acc[c][(int)a4.z], 1.0f);
            atomicAdd(&acc[c][(int)a4.w], 1.0f);
        }
    }
    __syncthreads();

    float* dst = (grp < 64) ? (es + grp * NEMB) : cnt;
#pragma unroll
    for (int k = 0; k < 2; ++k) {
        int j = tid + (k << 8);
        float v = acc[0][j] + acc[1][j] + acc[2][j] + acc[3][j]
                + acc[4][j] + acc[5][j] + acc[6][j] + acc[7][j];
        if (v != 0.f) atomicAdd(&dst[j], v);
    }
}

// fused finalize: 64 blocks x 512 threads. Block d: computes ncs (redundant, cheap),
// reduces n, writes row d of new_weight/new_embed_avg; block 0 also writes out_ncs.
__global__ void finalize_kernel(const float* __restrict__ cs_in, const float* __restrict__ avg_in,
                                const float* __restrict__ cnt_ws,
                                float* __restrict__ out_w, float* __restrict__ out_ncs,
                                float* __restrict__ avg_io /* es in, new_embed_avg out */) {
    __shared__ float red[NEMB];
    const int j = threadIdx.x;
    const int d = blockIdx.x;
    float c = cnt_ws[j];
    float nidx = (c == 0.f) ? 1.f : c;
    float ncs = DECAYF * cs_in[j] + OMDF * nidx;
    red[j] = ncs;
    __syncthreads();
    for (int s = 256; s > 0; s >>= 1) {
        if (j < s) red[j] += red[j + s];
        __syncthreads();
    }
    float n = red[0];
    float csj = (ncs + EPSF) / (n + (float)NEMB * EPSF) * n;
    int o = d * NEMB + j;
    float esv = avg_io[o];
    float navg = DECAYF * avg_in[o] + OMDF * esv;
    avg_io[o] = navg;
    out_w[o] = navg / csj;
    if (d == 0) out_ncs[j] = ncs;
}

extern "C" void kernel_launch(void* const* d_in, const int* in_sizes, int n_in,
                              void* d_out, int out_size, void* d_ws, size_t ws_size,
                              hipStream_t stream) {
    (void)in_sizes; (void)n_in; (void)out_size; (void)ws_size;
    const float* x   = (const float*)d_in[0];
    const float* w   = (const float*)d_in[1];
    const float* cs  = (const float*)d_in[2];
    const float* avg = (const float*)d_in[3];

    float* out = (float*)d_out;
    float* out_result = out;                 // 8388608
    float* out_arg    = out + 8388608;       // 131072
    float* out_w      = out + 8519680;       // 32768
    float* out_ncs    = out + 8552448;       // 512
    float* out_avg    = out + 8552960;       // 32768 (es accumulates here)

    char* wsb = (char*)d_ws;
    unsigned short* wh = (unsigned short*)wsb;             // 65536 B
    unsigned short* wl = (unsigned short*)(wsb + 65536);   // 65536 B
    float* wsq      = (float*)(wsb + 131072);              // 2048 B
    float* cnt_ws   = (float*)(wsb + 133120);              // 2048 B (counts)
    unsigned* gcnt  = (unsigned*)(wsb + 135168);           // 4 B (flag queue count)
    int* queue      = (int*)(wsb + 135232);                // 131072 B (flag queue)

    prep_kernel<<<9, 512, 0, stream>>>(w, wh, wl, wsq, cnt_ws, out_avg, gcnt);
    vq_main<<<2048, 128, 0, stream>>>(x, wh, wl, wsq, out_arg, gcnt, queue);
    refine_kernel<<<256, 256, 0, stream>>>(x, w, wsq, gcnt, queue, out_arg);
    finish_kernel<<<2080, 256, 0, stream>>>(x, w, out_arg, out_result, out_avg, cnt_ws);
    finalize_kernel<<<64, 512, 0, stream>>>(cs, avg, cnt_ws, out_w, out_ncs, out_avg);
}

// Round 2
// 189.732 us; speedup vs baseline: 1.1297x; 1.1297x over previous
//
#include <hip/hip_runtime.h>

#define NEMB 512
#define EMB 64
#define BSTR 262144          // 64*4096
#define DECAYF 0.99f
#define OMDF 0.01f
#define EPSF 1e-5f
#define GAP_T 0.012f
#define QCAP 32768           // flagged-token queue capacity (expect ~2-8K)

typedef __attribute__((ext_vector_type(8))) short bf16x8;
typedef __attribute__((ext_vector_type(4))) float f32x4;

__device__ __forceinline__ unsigned short f2bf(float f) {
    unsigned u = __float_as_uint(f);
    return (unsigned short)((u + 0x7FFFu + ((u >> 16) & 1u)) >> 16);   // RNE
}
__device__ __forceinline__ float bf2f(unsigned short h) {
    return __uint_as_float(((unsigned)h) << 16);
}

// 9 blocks x 512 threads.
// blocks 0-7: split w into bf16 hi/lo transposed [n][k].
// block 8: wsq + zero cnt_ws (512) + zero es region (32768) + zero flag queue count.
__global__ void prep_kernel(const float* __restrict__ w,
                            unsigned short* __restrict__ wh, unsigned short* __restrict__ wl,
                            float* __restrict__ wsq,
                            float* __restrict__ cnt_ws, float* __restrict__ es_region,
                            unsigned* __restrict__ gcnt) {
    int j = threadIdx.x;
    if (blockIdx.x < 8) {
        int d0 = blockIdx.x << 3;
        bf16x8 hb, lb;
#pragma unroll
        for (int i = 0; i < 8; ++i) {
            float v = w[(d0 + i) * NEMB + j];
            unsigned short h = f2bf(v);
            hb[i] = (short)h;
            lb[i] = (short)f2bf(v - bf2f(h));
        }
        *(bf16x8*)(wh + j * EMB + d0) = hb;
        *(bf16x8*)(wl + j * EMB + d0) = lb;
    } else {
        float s = 0.f;
#pragma unroll
        for (int d = 0; d < EMB; ++d) { float v = w[d * NEMB + j]; s = fmaf(v, v, s); }
        wsq[j] = s;
        cnt_ws[j] = 0.f;
        if (j == 0) *gcnt = 0u;
#pragma unroll
        for (int k = j; k < 32768; k += 512) es_region[k] = 0.f;
    }
}

#define UPD(S1, J1, S2, J2, s_, j_) do { \
    if (s_ < S1 || (s_ == S1 && j_ < J1)) { S2 = S1; J2 = J1; S1 = s_; J1 = j_; } \
    else if (s_ < S2 || (s_ == S2 && j_ < J2)) { S2 = s_; J2 = j_; } } while (0)

// 512 blocks x 512 threads: 256 tokens (4 h-rows) per block, 8 waves x 32 tokens.
// Theory-of-this-round: r1's loop streamed the full 128KB codebook from L2 per wave
// (512MB aggregate, depth-1 prefetch, ~300cy L2 hits) -> latency-bound at 74us with
// every pipe <26% busy. Fix: stage the codebook in LDS (two 256-code halves),
// XOR-swizzled (byte ^= (row&7)<<4 on BOTH write and read sides; the natural layout
// is a 16-way bank conflict: 16 lanes at 128B stride hit one bank). The 64KB
// codebook half UNIONs with the 64KB xt staging buffer -> 67KB LDS -> 2 blocks/CU,
// 16 waves/CU. x prologue is coalesced float4 -> LDS (r0-style), not the scalar
// stride-16KB herd of r1.
__global__ __launch_bounds__(512, 4) void vq_main(
    const float* __restrict__ x,
    const unsigned short* __restrict__ wh, const unsigned short* __restrict__ wl,
    const float* __restrict__ wsq,
    float* __restrict__ out_arg, unsigned* __restrict__ gcnt, int* __restrict__ queue)
{
    __shared__ __align__(16) unsigned char ubuf[65536];   // union: xt | codebook half
    __shared__ float wsq_s[NEMB];
    __shared__ float xsq_s[256];

    float* xt = (float*)ubuf;                         // [64][256] f32
    unsigned short* whs = (unsigned short*)ubuf;      // [256][64] bf16-hi, swizzled
    unsigned short* wls = whs + 16384;                // [256][64] bf16-lo, swizzled

    const int tid = threadIdx.x;
    const int blk = blockIdx.x;          // 512
    const int b    = blk >> 4;           // image
    const int hgrp = blk & 15;           // 4 h-rows per block
    const int t0 = b * 4096 + hgrp * 256;
    const float* xbase = x + b * BSTR + hgrp * 256;

    // ---- stage xt: 64 d-rows x 256 tokens, fully coalesced float4 ----
#pragma unroll
    for (int it = 0; it < 8; ++it) {
        int idx = tid + (it << 9);       // 0..4095 float4 units
        int d = idx >> 6, q = idx & 63;
        *(float4*)(xt + d * 256 + (q << 2)) = *(const float4*)(xbase + d * 4096 + (q << 2));
    }
    wsq_s[tid] = wsq[tid];               // 512 threads cover 512
    __syncthreads();

    // ---- per-token ||x||^2 ----
    if (tid < 256) {
        float s = 0.f;
#pragma unroll
        for (int d = 0; d < EMB; ++d) { float v = xt[d * 256 + tid]; s = fmaf(v, v, s); }
        xsq_s[tid] = s;
    }

    const int lane = tid & 63;
    const int wave = tid >> 6;           // 0..7
    const int l15  = lane & 15;
    const int quad = lane >> 4;
    const int wbase = wave << 5;         // 32 tokens per wave

    // ---- A fragments (hi/lo split bf16) from xt ----
    bf16x8 ah[2][2], al[2][2];
#pragma unroll
    for (int mt = 0; mt < 2; ++mt) {
        int m = wbase + (mt << 4) + l15;
#pragma unroll
        for (int ks = 0; ks < 2; ++ks) {
            int k0 = (ks << 5) + (quad << 3);
            bf16x8 hh, ll;
#pragma unroll
            for (int i = 0; i < 8; ++i) {
                float v = xt[(k0 + i) * 256 + m];
                unsigned short h = f2bf(v);
                hh[i] = (short)h;
                ll[i] = (short)f2bf(v - bf2f(h));
            }
            ah[mt][ks] = hh; al[mt][ks] = ll;
        }
    }
    __syncthreads();     // last read of xt; xsq_s ready

    float xq[2][4];
#pragma unroll
    for (int mt = 0; mt < 2; ++mt)
#pragma unroll
        for (int r = 0; r < 4; ++r)
            xq[mt][r] = xsq_s[wbase + (mt << 4) + (quad << 2) + r];

    float v1[2][4], v2[2][4];
    int   j1[2][4];
#pragma unroll
    for (int mt = 0; mt < 2; ++mt)
#pragma unroll
        for (int r = 0; r < 4; ++r) { v1[mt][r] = 3.4e38f; v2[mt][r] = 3.4e38f; j1[mt][r] = 0; }

    // swizzled read offsets (shorts). row&7 == l15&7 since rows step by 16.
    const int m7 = l15 & 7;
    const int s0off = ((quad ^ m7) << 3);          // chunk quad   (d = quad*8..)
    const int s1off = (((4 | quad) ^ m7) << 3);    // chunk 4+quad (d = 32+quad*8..)

    for (int half = 0; half < 2; ++half) {
        // ---- stage one 256-code half of the codebook (64KB) into the union ----
#pragma unroll
        for (int it = 0; it < 8; ++it) {
            int e = tid + (it << 9);     // 0..4095 16B units; arr uniform per iter
            int arr  = e >> 11;          // 0: hi, 1: lo
            int win  = e & 2047;
            int row  = win >> 3;         // code within half
            int slot = win & 7;          // 16B chunk within 128B row
            const unsigned short* src =
                (arr ? wl : wh) + ((half << 8) + row) * EMB + (slot << 3);
            bf16x8 v = *(const bf16x8*)src;
            unsigned short* dstb = arr ? wls : whs;
            *(bf16x8*)(dstb + row * EMB + ((slot ^ (row & 7)) << 3)) = v;
        }
        __syncthreads();

        const int nbase = half << 8;
#pragma unroll 2
        for (int it = 0; it < 16; ++it) {
            const int ib = ((it << 4) + l15) << 6;    // row*64 shorts
            bf16x8 b0 = *(const bf16x8*)(whs + ib + s0off);
            bf16x8 b1 = *(const bf16x8*)(whs + ib + s1off);
            bf16x8 b2 = *(const bf16x8*)(wls + ib + s0off);
            bf16x8 b3 = *(const bf16x8*)(wls + ib + s1off);
            const int n = nbase + (it << 4) + l15;
            float wq = wsq_s[n];

            f32x4 acc0 = (f32x4){0.f, 0.f, 0.f, 0.f};
            f32x4 acc1 = (f32x4){0.f, 0.f, 0.f, 0.f};
            acc0 = __builtin_amdgcn_mfma_f32_16x16x32_bf16(ah[0][0], b0, acc0, 0, 0, 0);
            acc1 = __builtin_amdgcn_mfma_f32_16x16x32_bf16(ah[1][0], b0, acc1, 0, 0, 0);
            acc0 = __builtin_amdgcn_mfma_f32_16x16x32_bf16(ah[0][1], b1, acc0, 0, 0, 0);
            acc1 = __builtin_amdgcn_mfma_f32_16x16x32_bf16(ah[1][1], b1, acc1, 0, 0, 0);
            acc0 = __builtin_amdgcn_mfma_f32_16x16x32_bf16(ah[0][0], b2, acc0, 0, 0, 0);
            acc1 = __builtin_amdgcn_mfma_f32_16x16x32_bf16(ah[1][0], b2, acc1, 0, 0, 0);
            acc0 = __builtin_amdgcn_mfma_f32_16x16x32_bf16(ah[0][1], b3, acc0, 0, 0, 0);
            acc1 = __builtin_amdgcn_mfma_f32_16x16x32_bf16(ah[1][1], b3, acc1, 0, 0, 0);
            acc0 = __builtin_amdgcn_mfma_f32_16x16x32_bf16(al[0][0], b0, acc0, 0, 0, 0);
            acc1 = __builtin_amdgcn_mfma_f32_16x16x32_bf16(al[1][0], b0, acc1, 0, 0, 0);
            acc0 = __builtin_amdgcn_mfma_f32_16x16x32_bf16(al[0][1], b1, acc0, 0, 0, 0);
            acc1 = __builtin_amdgcn_mfma_f32_16x16x32_bf16(al[1][1], b1, acc1, 0, 0, 0);

#pragma unroll
            for (int r = 0; r < 4; ++r) {
                float s0 = fmaf(-2.f, acc0[r], xq[0][r] + wq);
                bool p0 = s0 < v1[0][r];
                float mx0 = fmaxf(s0, v1[0][r]);
                v1[0][r] = fminf(s0, v1[0][r]);
                v2[0][r] = fminf(v2[0][r], mx0);
                j1[0][r] = p0 ? n : j1[0][r];

                float s1 = fmaf(-2.f, acc1[r], xq[1][r] + wq);
                bool p1 = s1 < v1[1][r];
                float mx1 = fmaxf(s1, v1[1][r]);
                v1[1][r] = fminf(s1, v1[1][r]);
                v2[1][r] = fminf(v2[1][r], mx1);
                j1[1][r] = p1 ? n : j1[1][r];
            }
        }
        __syncthreads();   // all reads done before restage (half 0) / exit (half 1)
    }

    // butterfly merge (v1,j1,v2) across the 16 lanes sharing each token
#pragma unroll
    for (int mt = 0; mt < 2; ++mt)
#pragma unroll
        for (int r = 0; r < 4; ++r) {
            float a1 = v1[mt][r], a2 = v2[mt][r];
            int   aj = j1[mt][r];
#pragma unroll
            for (int msk = 1; msk < 16; msk <<= 1) {
                float o1 = __shfl_xor(a1, msk, 64);
                int   oj = __shfl_xor(aj, msk, 64);
                float o2 = __shfl_xor(a2, msk, 64);
                bool take = (o1 < a1) || (o1 == a1 && oj < aj);
                float mx = fmaxf(a1, o1);
                a2 = fminf(fminf(a2, o2), mx);
                a1 = fminf(a1, o1);
                aj = take ? oj : aj;
            }
            v1[mt][r] = a1; v2[mt][r] = a2; j1[mt][r] = aj;
        }

    if (l15 == 0) {
#pragma unroll
        for (int mt = 0; mt < 2; ++mt)
#pragma unroll
            for (int r = 0; r < 4; ++r) {
                int gt = t0 + wbase + (mt << 4) + (quad << 2) + r;
                out_arg[gt] = (float)j1[mt][r];
                if (v2[mt][r] - v1[mt][r] < GAP_T) {
                    unsigned idx = atomicAdd(gcnt, 1u);     // global queue
                    if (idx < QCAP) queue[idx] = gt;
                }
            }
    }
}

// Globally balanced exact refine: 256 blocks x 256 threads = 1024 waves, each wave
// grabs flagged tokens with stride 1024 (no per-block tail). Exact fp32 scan over
// all 512 codes + f64 tie-break. Runs BEFORE finish, so finish sees final argmins.
__global__ __launch_bounds__(256) void refine_kernel(
    const float* __restrict__ x, const float* __restrict__ w,
    const float* __restrict__ wsq, const unsigned* __restrict__ gcnt,
    const int* __restrict__ queue, float* __restrict__ out_arg)
{
    __shared__ float wsq_s[NEMB];
    const int tid = threadIdx.x;
    wsq_s[tid] = wsq[tid];
    wsq_s[tid + 256] = wsq[tid + 256];
    __syncthreads();

    unsigned nfu = *gcnt;
    const int nf = (int)(nfu < (unsigned)QCAP ? nfu : (unsigned)QCAP);
    const int lane = tid & 63;
    const int gw = (blockIdx.x << 2) + (tid >> 6);

    for (int i = gw; i < nf; i += 1024) {
        const int t = queue[i];
        const int b = t >> 12, pos = t & 4095;
        float xd = x[b * BSTR + lane * 4096 + pos];   // x column, d = lane
        float xqv = xd * xd;
#pragma unroll
        for (int mk = 1; mk < 64; mk <<= 1) xqv += __shfl_xor(xqv, mk, 64);

        float accv[8];
#pragma unroll
        for (int k = 0; k < 8; ++k) accv[k] = 0.f;
#pragma unroll 4
        for (int d = 0; d < EMB; ++d) {
            float4 wa = *(const float4*)(w + d * NEMB + (lane << 2));
            float4 wb = *(const float4*)(w + d * NEMB + 256 + (lane << 2));
            float xv = __shfl(xd, d, 64);
            accv[0] = fmaf(xv, wa.x, accv[0]);
            accv[1] = fmaf(xv, wa.y, accv[1]);
            accv[2] = fmaf(xv, wa.z, accv[2]);
            accv[3] = fmaf(xv, wa.w, accv[3]);
            accv[4] = fmaf(xv, wb.x, accv[4]);
            accv[5] = fmaf(xv, wb.y, accv[5]);
            accv[6] = fmaf(xv, wb.z, accv[6]);
            accv[7] = fmaf(xv, wb.w, accv[7]);
        }

        float S1 = 3.4e38f, S2 = 3.4e38f; int J1 = 0, J2 = 0;
#pragma unroll
        for (int k = 0; k < 8; ++k) {
            int j = (k < 4) ? ((lane << 2) + k) : (256 + (lane << 2) + k - 4);
            float s = (xqv - 2.f * accv[k]) + wsq_s[j];
            UPD(S1, J1, S2, J2, s, j);
        }
#pragma unroll
        for (int mk = 1; mk < 64; mk <<= 1) {
            float os1 = __shfl_xor(S1, mk, 64); int oj1 = __shfl_xor(J1, mk, 64);
            float os2 = __shfl_xor(S2, mk, 64); int oj2 = __shfl_xor(J2, mk, 64);
            UPD(S1, J1, S2, J2, os1, oj1);
            UPD(S1, J1, S2, J2, os2, oj2);
        }

        int jm = J1;
        if (S2 - S1 < 1e-3f) {
            float w1 = w[lane * NEMB + J1];
            float w2 = w[lane * NEMB + J2];
            double e1 = (double)w1 * (double)w1 - 2.0 * (double)xd * (double)w1;
            double e2 = (double)w2 * (double)w2 - 2.0 * (double)xd * (double)w2;
#pragma unroll
            for (int mk = 1; mk < 64; mk <<= 1) {
                e1 += __shfl_xor(e1, mk, 64);
                e2 += __shfl_xor(e2, mk, 64);
            }
            if (e2 < e1 || (e2 == e1 && J2 < J1)) jm = J2;
        }
        if (lane == 0) out_arg[t] = (float)jm;
    }
}

// fused: result write + es/cnt accumulation. 8 d-grps x 64 chunks = 512 blocks x 512.
// Each block handles 8 d-rows for 2048 tokens: arg is read ONCE per 8 d's (4MB total
// vs r1's 34MB of 65x redundant re-reads). LDS wrow gather + coalesced stores kept.
__global__ __launch_bounds__(512) void finish_kernel(
    const float* __restrict__ x, const float* __restrict__ w, const float* __restrict__ arg,
    float* __restrict__ out_result,
    float* __restrict__ es, float* __restrict__ cnt)
{
    __shared__ float wrow8[8 * 512];     // 16KB
    __shared__ float acc8[8 * 513];      // 16.4KB, 513-stride: bank = (d + j) % 32
    __shared__ float cacc[513];
    const int tid = threadIdx.x;
    const int grp = blockIdx.x >> 6;     // 0..7  (8 d's each)
    const int chunk = blockIdx.x & 63;   // 2048 tokens each

#pragma unroll
    for (int d = 0; d < 8; ++d) {
        wrow8[(d << 9) + tid] = w[((grp << 3) + d) * NEMB + tid];
        acc8[d * 513 + tid] = 0.f;
    }
    if (tid < 8) acc8[tid * 513 + 512] = 0.f;
    cacc[tid] = 0.f;
    if (tid == 0) cacc[512] = 0.f;
    __syncthreads();

    const int t = (chunk << 11) + (tid << 2);   // 4 consecutive tokens
    const int b = t >> 12;
    const int o = b * BSTR + (t & 4095);
    float4 a4 = *(const float4*)(arg + t);
    int j0 = (int)a4.x, j1 = (int)a4.y, j2 = (int)a4.z, j3 = (int)a4.w;
    if (grp == 0) {
        atomicAdd(&cacc[j0], 1.f);
        atomicAdd(&cacc[j1], 1.f);
        atomicAdd(&cacc[j2], 1.f);
        atomicAdd(&cacc[j3], 1.f);
    }
#pragma unroll
    for (int d = 0; d < 8; ++d) {
        const int dg = (grp << 3) + d;
        float4 x4 = *(const float4*)(x + o + dg * 4096);
        float* ad = acc8 + d * 513;
        atomicAdd(&ad[j0], x4.x);
        atomicAdd(&ad[j1], x4.y);
        atomicAdd(&ad[j2], x4.z);
        atomicAdd(&ad[j3], x4.w);
        float4 r4 = {wrow8[(d << 9) + j0], wrow8[(d << 9) + j1],
                     wrow8[(d << 9) + j2], wrow8[(d << 9) + j3]};
        *(float4*)(out_result + o + dg * 4096) = r4;
    }
    __syncthreads();

#pragma unroll
    for (int d = 0; d < 8; ++d) {
        float v = acc8[d * 513 + tid];
        if (v != 0.f) atomicAdd(&es[((grp << 3) + d) * NEMB + tid], v);
    }
    if (grp == 0) {
        float cv = cacc[tid];
        if (cv != 0.f) atomicAdd(&cnt[tid], cv);
    }
}

// fused finalize: 64 blocks x 512 threads. Block d: computes ncs (redundant, cheap),
// reduces n, writes row d of new_weight/new_embed_avg; block 0 also writes out_ncs.
__global__ void finalize_kernel(const float* __restrict__ cs_in, const float* __restrict__ avg_in,
                                const float* __restrict__ cnt_ws,
                                float* __restrict__ out_w, float* __restrict__ out_ncs,
                                float* __restrict__ avg_io /* es in, new_embed_avg out */) {
    __shared__ float red[NEMB];
    const int j = threadIdx.x;
    const int d = blockIdx.x;
    float c = cnt_ws[j];
    float nidx = (c == 0.f) ? 1.f : c;
    float ncs = DECAYF * cs_in[j] + OMDF * nidx;
    red[j] = ncs;
    __syncthreads();
    for (int s = 256; s > 0; s >>= 1) {
        if (j < s) red[j] += red[j + s];
        __syncthreads();
    }
    float n = red[0];
    float csj = (ncs + EPSF) / (n + (float)NEMB * EPSF) * n;
    int o = d * NEMB + j;
    float esv = avg_io[o];
    float navg = DECAYF * avg_in[o] + OMDF * esv;
    avg_io[o] = navg;
    out_w[o] = navg / csj;
    if (d == 0) out_ncs[j] = ncs;
}

extern "C" void kernel_launch(void* const* d_in, const int* in_sizes, int n_in,
                              void* d_out, int out_size, void* d_ws, size_t ws_size,
                              hipStream_t stream) {
    (void)in_sizes; (void)n_in; (void)out_size; (void)ws_size;
    const float* x   = (const float*)d_in[0];
    const float* w   = (const float*)d_in[1];
    const float* cs  = (const float*)d_in[2];
    const float* avg = (const float*)d_in[3];

    float* out = (float*)d_out;
    float* out_result = out;                 // 8388608
    float* out_arg    = out + 8388608;       // 131072
    float* out_w      = out + 8519680;       // 32768
    float* out_ncs    = out + 8552448;       // 512
    float* out_avg    = out + 8552960;       // 32768 (es accumulates here)

    char* wsb = (char*)d_ws;
    unsigned short* wh = (unsigned short*)wsb;             // 65536 B
    unsigned short* wl = (unsigned short*)(wsb + 65536);   // 65536 B
    float* wsq      = (float*)(wsb + 131072);              // 2048 B
    float* cnt_ws   = (float*)(wsb + 133120);              // 2048 B (counts)
    unsigned* gcnt  = (unsigned*)(wsb + 135168);           // 4 B (flag queue count)
    int* queue      = (int*)(wsb + 135232);                // 131072 B (flag queue)

    prep_kernel<<<9, 512, 0, stream>>>(w, wh, wl, wsq, cnt_ws, out_avg, gcnt);
    vq_main<<<512, 512, 0, stream>>>(x, wh, wl, wsq, out_arg, gcnt, queue);
    refine_kernel<<<256, 256, 0, stream>>>(x, w, wsq, gcnt, queue, out_arg);
    finish_kernel<<<512, 512, 0, stream>>>(x, w, out_arg, out_result, out_avg, cnt_ws);
    finalize_kernel<<<64, 512, 0, stream>>>(cs, avg, cnt_ws, out_w, out_ncs, out_avg);
}

// Round 5
// 182.518 us; speedup vs baseline: 1.1744x; 1.0395x over previous
//
#include <hip/hip_runtime.h>

#define NEMB 512
#define EMB 64
#define BSTR 262144          // 64*4096
#define DECAYF 0.99f
#define OMDF 0.01f
#define EPSF 1e-5f
#define GAP_T 0.012f
#define QCAP 32768           // flagged-token queue capacity (expect ~2-8K)

typedef __attribute__((ext_vector_type(8))) short bf16x8;
typedef __attribute__((ext_vector_type(4))) float f32x4;

__device__ __forceinline__ unsigned short f2bf(float f) {
    unsigned u = __float_as_uint(f);
    return (unsigned short)((u + 0x7FFFu + ((u >> 16) & 1u)) >> 16);   // RNE
}
__device__ __forceinline__ float bf2f(unsigned short h) {
    return __uint_as_float(((unsigned)h) << 16);
}

// 9 blocks x 512 threads.
// blocks 0-7: split w into bf16 hi/lo transposed [n][k].
// block 8: wsq + zero cnt_ws (512) + zero flag queue count.
__global__ void prep_kernel(const float* __restrict__ w,
                            unsigned short* __restrict__ wh, unsigned short* __restrict__ wl,
                            float* __restrict__ wsq,
                            float* __restrict__ cnt_ws, unsigned* __restrict__ gcnt) {
    int j = threadIdx.x;
    if (blockIdx.x < 8) {
        int d0 = blockIdx.x << 3;
        bf16x8 hb, lb;
#pragma unroll
        for (int i = 0; i < 8; ++i) {
            float v = w[(d0 + i) * NEMB + j];
            unsigned short h = f2bf(v);
            hb[i] = (short)h;
            lb[i] = (short)f2bf(v - bf2f(h));
        }
        *(bf16x8*)(wh + j * EMB + d0) = hb;
        *(bf16x8*)(wl + j * EMB + d0) = lb;
    } else {
        float s = 0.f;
#pragma unroll
        for (int d = 0; d < EMB; ++d) { float v = w[d * NEMB + j]; s = fmaf(v, v, s); }
        wsq[j] = s;
        cnt_ws[j] = 0.f;
        if (j == 0) *gcnt = 0u;
    }
}

#define UPD(S1, J1, S2, J2, s_, j_) do { \
    if (s_ < S1 || (s_ == S1 && j_ < J1)) { S2 = S1; J2 = J1; S1 = s_; J1 = j_; } \
    else if (s_ < S2 || (s_ == S2 && j_ < J2)) { S2 = s_; J2 = j_; } } while (0)

// 512 blocks x 512 threads: 256 tokens (4 h-rows) per block, 8 waves x 32 tokens.
// Codebook staged in LDS in two 256-code halves, XOR-swizzled (r2-verified).
__global__ __launch_bounds__(512, 4) void vq_main(
    const float* __restrict__ x,
    const unsigned short* __restrict__ wh, const unsigned short* __restrict__ wl,
    const float* __restrict__ wsq,
    float* __restrict__ out_arg, unsigned* __restrict__ gcnt, int* __restrict__ queue)
{
    __shared__ __align__(16) unsigned char ubuf[65536];   // union: xt | codebook half
    __shared__ float wsq_s[NEMB];
    __shared__ float xsq_s[256];

    float* xt = (float*)ubuf;                         // [64][256] f32
    unsigned short* whs = (unsigned short*)ubuf;      // [256][64] bf16-hi, swizzled
    unsigned short* wls = whs + 16384;                // [256][64] bf16-lo, swizzled

    const int tid = threadIdx.x;
    const int blk = blockIdx.x;          // 512
    const int b    = blk >> 4;           // image
    const int hgrp = blk & 15;           // 4 h-rows per block
    const int t0 = b * 4096 + hgrp * 256;
    const float* xbase = x + b * BSTR + hgrp * 256;

    // ---- stage xt: 64 d-rows x 256 tokens, fully coalesced float4 ----
#pragma unroll
    for (int it = 0; it < 8; ++it) {
        int idx = tid + (it << 9);       // 0..4095 float4 units
        int d = idx >> 6, q = idx & 63;
        *(float4*)(xt + d * 256 + (q << 2)) = *(const float4*)(xbase + d * 4096 + (q << 2));
    }
    wsq_s[tid] = wsq[tid];               // 512 threads cover 512
    __syncthreads();

    // ---- per-token ||x||^2 ----
    if (tid < 256) {
        float s = 0.f;
#pragma unroll
        for (int d = 0; d < EMB; ++d) { float v = xt[d * 256 + tid]; s = fmaf(v, v, s); }
        xsq_s[tid] = s;
    }

    const int lane = tid & 63;
    const int wave = tid >> 6;           // 0..7
    const int l15  = lane & 15;
    const int quad = lane >> 4;
    const int wbase = wave << 5;         // 32 tokens per wave

    // ---- A fragments (hi/lo split bf16) from xt ----
    bf16x8 ah[2][2], al[2][2];
#pragma unroll
    for (int mt = 0; mt < 2; ++mt) {
        int m = wbase + (mt << 4) + l15;
#pragma unroll
        for (int ks = 0; ks < 2; ++ks) {
            int k0 = (ks << 5) + (quad << 3);
            bf16x8 hh, ll;
#pragma unroll
            for (int i = 0; i < 8; ++i) {
                float v = xt[(k0 + i) * 256 + m];
                unsigned short h = f2bf(v);
                hh[i] = (short)h;
                ll[i] = (short)f2bf(v - bf2f(h));
            }
            ah[mt][ks] = hh; al[mt][ks] = ll;
        }
    }
    __syncthreads();     // last read of xt; xsq_s ready

    float xq[2][4];
#pragma unroll
    for (int mt = 0; mt < 2; ++mt)
#pragma unroll
        for (int r = 0; r < 4; ++r)
            xq[mt][r] = xsq_s[wbase + (mt << 4) + (quad << 2) + r];

    float v1[2][4], v2[2][4];
    int   j1[2][4];
#pragma unroll
    for (int mt = 0; mt < 2; ++mt)
#pragma unroll
        for (int r = 0; r < 4; ++r) { v1[mt][r] = 3.4e38f; v2[mt][r] = 3.4e38f; j1[mt][r] = 0; }

    // swizzled read offsets (shorts). row&7 == l15&7 since rows step by 16.
    const int m7 = l15 & 7;
    const int s0off = ((quad ^ m7) << 3);          // chunk quad   (d = quad*8..)
    const int s1off = (((4 | quad) ^ m7) << 3);    // chunk 4+quad (d = 32+quad*8..)

    for (int half = 0; half < 2; ++half) {
        // ---- stage one 256-code half of the codebook (64KB) into the union ----
#pragma unroll
        for (int it = 0; it < 8; ++it) {
            int e = tid + (it << 9);     // 0..4095 16B units; arr uniform per iter
            int arr  = e >> 11;          // 0: hi, 1: lo
            int win  = e & 2047;
            int row  = win >> 3;         // code within half
            int slot = win & 7;          // 16B chunk within 128B row
            const unsigned short* src =
                (arr ? wl : wh) + ((half << 8) + row) * EMB + (slot << 3);
            bf16x8 v = *(const bf16x8*)src;
            unsigned short* dstb = arr ? wls : whs;
            *(bf16x8*)(dstb + row * EMB + ((slot ^ (row & 7)) << 3)) = v;
        }
        __syncthreads();

        const int nbase = half << 8;
#pragma unroll 2
        for (int it = 0; it < 16; ++it) {
            const int ib = ((it << 4) + l15) << 6;    // row*64 shorts
            bf16x8 b0 = *(const bf16x8*)(whs + ib + s0off);
            bf16x8 b1 = *(const bf16x8*)(whs + ib + s1off);
            bf16x8 b2 = *(const bf16x8*)(wls + ib + s0off);
            bf16x8 b3 = *(const bf16x8*)(wls + ib + s1off);
            const int n = nbase + (it << 4) + l15;
            float wq = wsq_s[n];

            f32x4 acc0 = (f32x4){0.f, 0.f, 0.f, 0.f};
            f32x4 acc1 = (f32x4){0.f, 0.f, 0.f, 0.f};
            acc0 = __builtin_amdgcn_mfma_f32_16x16x32_bf16(ah[0][0], b0, acc0, 0, 0, 0);
            acc1 = __builtin_amdgcn_mfma_f32_16x16x32_bf16(ah[1][0], b0, acc1, 0, 0, 0);
            acc0 = __builtin_amdgcn_mfma_f32_16x16x32_bf16(ah[0][1], b1, acc0, 0, 0, 0);
            acc1 = __builtin_amdgcn_mfma_f32_16x16x32_bf16(ah[1][1], b1, acc1, 0, 0, 0);
            acc0 = __builtin_amdgcn_mfma_f32_16x16x32_bf16(ah[0][0], b2, acc0, 0, 0, 0);
            acc1 = __builtin_amdgcn_mfma_f32_16x16x32_bf16(ah[1][0], b2, acc1, 0, 0, 0);
            acc0 = __builtin_amdgcn_mfma_f32_16x16x32_bf16(ah[0][1], b3, acc0, 0, 0, 0);
            acc1 = __builtin_amdgcn_mfma_f32_16x16x32_bf16(ah[1][1], b3, acc1, 0, 0, 0);
            acc0 = __builtin_amdgcn_mfma_f32_16x16x32_bf16(al[0][0], b0, acc0, 0, 0, 0);
            acc1 = __builtin_amdgcn_mfma_f32_16x16x32_bf16(al[1][0], b0, acc1, 0, 0, 0);
            acc0 = __builtin_amdgcn_mfma_f32_16x16x32_bf16(al[0][1], b1, acc0, 0, 0, 0);
            acc1 = __builtin_amdgcn_mfma_f32_16x16x32_bf16(al[1][1], b1, acc1, 0, 0, 0);

#pragma unroll
            for (int r = 0; r < 4; ++r) {
                float s0 = fmaf(-2.f, acc0[r], xq[0][r] + wq);
                bool p0 = s0 < v1[0][r];
                float mx0 = fmaxf(s0, v1[0][r]);
                v1[0][r] = fminf(s0, v1[0][r]);
                v2[0][r] = fminf(v2[0][r], mx0);
                j1[0][r] = p0 ? n : j1[0][r];

                float s1 = fmaf(-2.f, acc1[r], xq[1][r] + wq);
                bool p1 = s1 < v1[1][r];
                float mx1 = fmaxf(s1, v1[1][r]);
                v1[1][r] = fminf(s1, v1[1][r]);
                v2[1][r] = fminf(v2[1][r], mx1);
                j1[1][r] = p1 ? n : j1[1][r];
            }
        }
        __syncthreads();   // all reads done before restage (half 0) / exit (half 1)
    }

    // butterfly merge (v1,j1,v2) across the 16 lanes sharing each token
#pragma unroll
    for (int mt = 0; mt < 2; ++mt)
#pragma unroll
        for (int r = 0; r < 4; ++r) {
            float a1 = v1[mt][r], a2 = v2[mt][r];
            int   aj = j1[mt][r];
#pragma unroll
            for (int msk = 1; msk < 16; msk <<= 1) {
                float o1 = __shfl_xor(a1, msk, 64);
                int   oj = __shfl_xor(aj, msk, 64);
                float o2 = __shfl_xor(a2, msk, 64);
                bool take = (o1 < a1) || (o1 == a1 && oj < aj);
                float mx = fmaxf(a1, o1);
                a2 = fminf(fminf(a2, o2), mx);
                a1 = fminf(a1, o1);
                aj = take ? oj : aj;
            }
            v1[mt][r] = a1; v2[mt][r] = a2; j1[mt][r] = aj;
        }

    if (l15 == 0) {
#pragma unroll
        for (int mt = 0; mt < 2; ++mt)
#pragma unroll
            for (int r = 0; r < 4; ++r) {
                int gt = t0 + wbase + (mt << 4) + (quad << 2) + r;
                out_arg[gt] = (float)j1[mt][r];
                if (v2[mt][r] - v1[mt][r] < GAP_T) {
                    unsigned idx = atomicAdd(gcnt, 1u);     // global queue
                    if (idx < QCAP) queue[idx] = gt;
                }
            }
    }
}

// Globally balanced exact refine (unchanged). Runs before es/result so arg is final.
__global__ __launch_bounds__(256) void refine_kernel(
    const float* __restrict__ x, const float* __restrict__ w,
    const float* __restrict__ wsq, const unsigned* __restrict__ gcnt,
    const int* __restrict__ queue, float* __restrict__ out_arg)
{
    __shared__ float wsq_s[NEMB];
    const int tid = threadIdx.x;
    wsq_s[tid] = wsq[tid];
    wsq_s[tid + 256] = wsq[tid + 256];
    __syncthreads();

    unsigned nfu = *gcnt;
    const int nf = (int)(nfu < (unsigned)QCAP ? nfu : (unsigned)QCAP);
    const int lane = tid & 63;
    const int gw = (blockIdx.x << 2) + (tid >> 6);

    for (int i = gw; i < nf; i += 1024) {
        const int t = queue[i] & 131071;              // hardened: in-range token id
        const int b = t >> 12, pos = t & 4095;
        float xd = x[b * BSTR + lane * 4096 + pos];   // x column, d = lane
        float xqv = xd * xd;
#pragma unroll
        for (int mk = 1; mk < 64; mk <<= 1) xqv += __shfl_xor(xqv, mk, 64);

        float accv[8];
#pragma unroll
        for (int k = 0; k < 8; ++k) accv[k] = 0.f;
#pragma unroll 4
        for (int d = 0; d < EMB; ++d) {
            float4 wa = *(const float4*)(w + d * NEMB + (lane << 2));
            float4 wb = *(const float4*)(w + d * NEMB + 256 + (lane << 2));
            float xv = __shfl(xd, d, 64);
            accv[0] = fmaf(xv, wa.x, accv[0]);
            accv[1] = fmaf(xv, wa.y, accv[1]);
            accv[2] = fmaf(xv, wa.z, accv[2]);
            accv[3] = fmaf(xv, wa.w, accv[3]);
            accv[4] = fmaf(xv, wb.x, accv[4]);
            accv[5] = fmaf(xv, wb.y, accv[5]);
            accv[6] = fmaf(xv, wb.z, accv[6]);
            accv[7] = fmaf(xv, wb.w, accv[7]);
        }

        float S1 = 3.4e38f, S2 = 3.4e38f; int J1 = 0, J2 = 0;
#pragma unroll
        for (int k = 0; k < 8; ++k) {
            int j = (k < 4) ? ((lane << 2) + k) : (256 + (lane << 2) + k - 4);
            float s = (xqv - 2.f * accv[k]) + wsq_s[j];
            UPD(S1, J1, S2, J2, s, j);
        }
#pragma unroll
        for (int mk = 1; mk < 64; mk <<= 1) {
            float os1 = __shfl_xor(S1, mk, 64); int oj1 = __shfl_xor(J1, mk, 64);
            float os2 = __shfl_xor(S2, mk, 64); int oj2 = __shfl_xor(J2, mk, 64);
            UPD(S1, J1, S2, J2, os1, oj1);
            UPD(S1, J1, S2, J2, os2, oj2);
        }

        int jm = J1;
        if (S2 - S1 < 1e-3f) {
            float w1 = w[lane * NEMB + J1];
            float w2 = w[lane * NEMB + J2];
            double e1 = (double)w1 * (double)w1 - 2.0 * (double)xd * (double)w1;
            double e2 = (double)w2 * (double)w2 - 2.0 * (double)xd * (double)w2;
#pragma unroll
            for (int mk = 1; mk < 64; mk <<= 1) {
                e1 += __shfl_xor(e1, mk, 64);
                e2 += __shfl_xor(e2, mk, 64);
            }
            if (e2 < e1 || (e2 == e1 && J2 < J1)) jm = J2;
        }
        if (lane == 0) out_arg[t] = (float)jm;
    }
}

// ATOMIC-FREE es: es = x_flat^T @ onehot computed by MFMA (split-bf16 x, exact-bf16
// onehot built in registers from arg). Grid 256 = 2 j-flavors x 128 token-chunks.
// r4 BUG FIXED: onehot compare must use the GLOBAL code id (flavor*256 + local j);
// r4 compared against the local j, so flavor-1 blocks recomputed codes 0..255 and
// es[:,256:512] was garbage (output-2 absmax 238).
__global__ __launch_bounds__(512) void es_kernel(
    const float* __restrict__ x, const float* __restrict__ arg,
    float* __restrict__ es_p, float* __restrict__ cnt_ws)
{
    __shared__ unsigned short xh[16384];   // [64][256] bf16-hi, 16B chunks XOR-swizzled
    __shared__ unsigned short xl[16384];   // bf16-lo
    __shared__ int args_s[256];
    __shared__ float cacc[NEMB];

    const int tid = threadIdx.x;
    const int blk = blockIdx.x;          // 256
    const int flavor = blk >> 7;         // j range [flavor*256, +256)
    const int chunk = blk & 127;         // 1024 tokens
    const int b = chunk >> 2;            // image (4096 tokens each)
    const int tpos0 = (chunk & 3) << 10; // within-image token offset

    cacc[tid] = 0.f;

    const int lane = tid & 63;
    const int wave = tid >> 6;           // 0..7
    const int l15  = lane & 15;
    const int quad = lane >> 4;
    const int jb   = wave << 5;          // 32 local j per wave (2 n-chunks)

    f32x4 acc[4][2];
#pragma unroll
    for (int m = 0; m < 4; ++m)
#pragma unroll
        for (int nc = 0; nc < 2; ++nc) acc[m][nc] = (f32x4){0.f, 0.f, 0.f, 0.f};

    for (int st = 0; st < 4; ++st) {
        const int tpos = tpos0 + (st << 8);          // within-image
        // ---- stage 64 d x 256 tokens as swizzled hi/lo bf16 ----
#pragma unroll
        for (int it = 0; it < 8; ++it) {
            int idx = tid + (it << 9);               // 0..4095 float4 units
            int d = idx >> 6, q = idx & 63;          // q: 4-token group
            float4 g = *(const float4*)(x + b * BSTR + d * 4096 + tpos + (q << 2));
            unsigned short h0 = f2bf(g.x), h1 = f2bf(g.y), h2 = f2bf(g.z), h3 = f2bf(g.w);
            unsigned short e0 = f2bf(g.x - bf2f(h0)), e1 = f2bf(g.y - bf2f(h1));
            unsigned short e2 = f2bf(g.z - bf2f(h2)), e3 = f2bf(g.w - bf2f(h3));
            int c = q >> 1, half = q & 1;            // 16B chunk, 8B half
            int off = d * 256 + ((c ^ (d & 7)) << 3) + (half << 2);
            ushort4 hv = {h0, h1, h2, h3};
            ushort4 lv = {e0, e1, e2, e3};
            *(ushort4*)(xh + off) = hv;
            *(ushort4*)(xl + off) = lv;
        }
        if (tid < 256) args_s[tid] = ((int)arg[b * 4096 + tpos + tid]) & 511;  // hardened
        __syncthreads();

        if (flavor == 0 && tid < 256) atomicAdd(&cacc[args_s[tid]], 1.f);

        // ---- MFMA: A = x^T (d-rows, token-k), B = onehot (token-k, j-cols) ----
#pragma unroll
        for (int kk = 0; kk < 8; ++kk) {
            bf16x8 ah[4], al[4];
#pragma unroll
            for (int m = 0; m < 4; ++m) {
                int d = (m << 4) + l15;
                int coff = ((((kk << 2) + quad) ^ (d & 7)) << 3);
                ah[m] = *(const bf16x8*)(xh + d * 256 + coff);
                al[m] = *(const bf16x8*)(xl + d * 256 + coff);
            }
            int argv[8];
            const int kb = (kk << 5) + (quad << 3);
#pragma unroll
            for (int i = 0; i < 8; ++i) argv[i] = args_s[kb + i];
#pragma unroll
            for (int nc = 0; nc < 2; ++nc) {
                const int jg = (flavor << 8) + jb + (nc << 4) + l15;   // GLOBAL code id
                bf16x8 bf;
#pragma unroll
                for (int i = 0; i < 8; ++i) bf[i] = (argv[i] == jg) ? (short)0x3F80 : (short)0;
#pragma unroll
                for (int m = 0; m < 4; ++m) {
                    acc[m][nc] = __builtin_amdgcn_mfma_f32_16x16x32_bf16(ah[m], bf, acc[m][nc], 0, 0, 0);
                    acc[m][nc] = __builtin_amdgcn_mfma_f32_16x16x32_bf16(al[m], bf, acc[m][nc], 0, 0, 0);
                }
            }
        }
        __syncthreads();    // all reads (and hist adds) done before restage
    }

    // ---- flush deterministic partial: es_p[blk][d][jl] (jl local to flavor) ----
    float* ep = es_p + blk * 16384;
#pragma unroll
    for (int m = 0; m < 4; ++m)
#pragma unroll
        for (int nc = 0; nc < 2; ++nc) {
            const int jl = jb + (nc << 4) + l15;
#pragma unroll
            for (int r = 0; r < 4; ++r) {
                const int d = (m << 4) + (quad << 2) + r;
                ep[d * 256 + jl] = acc[m][nc][r];
            }
        }
    if (flavor == 0) {
        float v = cacc[tid];
        if (v != 0.f) atomicAdd(&cnt_ws[tid], v);
    }
}

// fused finalize + es partial reduction: 128 blocks (64 d x 2 j-halves) x 256 thr.
// Reads 128 partials per (d,j) — coalesced 1KB rows, L2/L3-resident.
__global__ __launch_bounds__(256) void finalize_kernel(
    const float* __restrict__ cs_in, const float* __restrict__ avg_in,
    const float* __restrict__ cnt_ws, const float* __restrict__ es_p,
    float* __restrict__ out_w, float* __restrict__ out_ncs,
    float* __restrict__ out_avg) {
    __shared__ float red[256];
    const int tid = threadIdx.x;
    const int d  = blockIdx.x >> 1;
    const int jh = blockIdx.x & 1;

    float c0 = cnt_ws[tid], c1 = cnt_ws[tid + 256];
    float ncs0 = DECAYF * cs_in[tid] + OMDF * ((c0 == 0.f) ? 1.f : c0);
    float ncs1 = DECAYF * cs_in[tid + 256] + OMDF * ((c1 == 0.f) ? 1.f : c1);
    red[tid] = ncs0 + ncs1;
    __syncthreads();
    for (int s = 128; s > 0; s >>= 1) {
        if (tid < s) red[tid] += red[tid + s];
        __syncthreads();
    }
    const float n = red[0];

    const float* ep = es_p + (jh << 7) * 16384 + d * 256 + tid;
    float s = 0.f;
#pragma unroll 16
    for (int c = 0; c < 128; ++c) s += ep[c * 16384];

    const float ncs = jh ? ncs1 : ncs0;
    const float csj = (ncs + EPSF) / (n + (float)NEMB * EPSF) * n;
    const int o = d * NEMB + (jh << 8) + tid;
    const float navg = DECAYF * avg_in[o] + OMDF * s;
    out_avg[o] = navg;
    out_w[o] = navg / csj;
    if (blockIdx.x == 0) { out_ncs[tid] = ncs0; out_ncs[tid + 256] = ncs1; }
}

// pure gather result write: out_result[b,d,t] = w[d, arg[t]]. No x read, no atomics.
// 8 d-grps x 64 chunks = 512 blocks x 512. Runs LAST (out_result overlays es_p).
__global__ __launch_bounds__(512) void result_kernel(
    const float* __restrict__ w, const float* __restrict__ arg,
    float* __restrict__ out_result)
{
    __shared__ float wrow8[8 * 512];
    const int tid = threadIdx.x;
    const int grp = blockIdx.x >> 6;     // 0..7  (8 d's each)
    const int chunk = blockIdx.x & 63;   // 2048 tokens each
#pragma unroll
    for (int d = 0; d < 8; ++d)
        wrow8[(d << 9) + tid] = w[((grp << 3) + d) * NEMB + tid];
    __syncthreads();

    const int t = (chunk << 11) + (tid << 2);   // 4 consecutive tokens
    const int o = (t >> 12) * BSTR + (t & 4095);
    float4 a4 = *(const float4*)(arg + t);
    int j0 = ((int)a4.x) & 511, j1 = ((int)a4.y) & 511;     // hardened
    int j2 = ((int)a4.z) & 511, j3 = ((int)a4.w) & 511;
#pragma unroll
    for (int d = 0; d < 8; ++d) {
        const int dg = (grp << 3) + d;
        float4 r4 = {wrow8[(d << 9) + j0], wrow8[(d << 9) + j1],
                     wrow8[(d << 9) + j2], wrow8[(d << 9) + j3]};
        *(float4*)(out_result + o + dg * 4096) = r4;
    }
}

extern "C" void kernel_launch(void* const* d_in, const int* in_sizes, int n_in,
                              void* d_out, int out_size, void* d_ws, size_t ws_size,
                              hipStream_t stream) {
    (void)in_sizes; (void)n_in; (void)out_size; (void)ws_size;
    const float* x   = (const float*)d_in[0];
    const float* w   = (const float*)d_in[1];
    const float* cs  = (const float*)d_in[2];
    const float* avg = (const float*)d_in[3];

    float* out = (float*)d_out;
    float* out_result = out;                 // 8388608 floats
    float* out_arg    = out + 8388608;       // 131072
    float* out_w      = out + 8519680;       // 32768
    float* out_ncs    = out + 8552448;       // 512
    float* out_avg    = out + 8552960;       // 32768
    float* es_p       = out;                 // 16MB scratch inside out_result region;
                                             // consumed by finalize BEFORE result_kernel writes

    char* wsb = (char*)d_ws;
    unsigned short* wh = (unsigned short*)wsb;             // 65536 B
    unsigned short* wl = (unsigned short*)(wsb + 65536);   // 65536 B
    float* wsq      = (float*)(wsb + 131072);              // 2048 B
    float* cnt_ws   = (float*)(wsb + 133120);              // 2048 B (counts)
    unsigned* gcnt  = (unsigned*)(wsb + 135168);           // 4 B (flag queue count)
    int* queue      = (int*)(wsb + 135232);                // 131072 B (flag queue)

    prep_kernel<<<9, 512, 0, stream>>>(w, wh, wl, wsq, cnt_ws, gcnt);
    vq_main<<<512, 512, 0, stream>>>(x, wh, wl, wsq, out_arg, gcnt, queue);
    refine_kernel<<<256, 256, 0, stream>>>(x, w, wsq, gcnt, queue, out_arg);
    es_kernel<<<256, 512, 0, stream>>>(x, out_arg, es_p, cnt_ws);
    finalize_kernel<<<128, 256, 0, stream>>>(cs, avg, cnt_ws, es_p, out_w, out_ncs, out_avg);
    result_kernel<<<512, 512, 0, stream>>>(w, out_arg, out_result);
}